// Round 11
// baseline (196.713 us; speedup 1.0000x reference)
//
#include <hip/hip_runtime.h>

typedef __attribute__((ext_vector_type(8))) __bf16 bf16x8;
typedef __attribute__((ext_vector_type(8))) unsigned short ushort8;
typedef __attribute__((ext_vector_type(4))) unsigned short ushort4v;
typedef __attribute__((ext_vector_type(4))) float f32x4;
typedef __attribute__((ext_vector_type(2))) _Float16 f16x2;
typedef __attribute__((ext_vector_type(4))) _Float16 f16x4;
typedef __attribute__((ext_vector_type(8))) _Float16 f16x8;
typedef __attribute__((ext_vector_type(2))) __fp16 fp16v2;

__device__ __forceinline__ unsigned short f2bf(float f) {
    union { float f; unsigned int u; } c; c.f = f;
    unsigned int u = c.u;
    u += 0x7fffu + ((u >> 16) & 1u);
    return (unsigned short)(u >> 16);
}

__device__ __forceinline__ unsigned short f2h(float f) {
    _Float16 h = (_Float16)f;
    return __builtin_bit_cast(unsigned short, h);
}

// async global->LDS, 16 B per lane; LDS dest = wave-uniform base + lane*16
__device__ __forceinline__ void async16(const void* g, void* l) {
    __builtin_amdgcn_global_load_lds(
        (const __attribute__((address_space(1))) unsigned int*)g,
        (__attribute__((address_space(3))) unsigned int*)l, 16, 0, 0);
}

// ---------------- fused fp32 -> bf16/f16 conversion for all 5 tensors ----------------
// r17: wo converts to f16 (out_gemm runs f16 MFMA; ctx from attn is f16 too).
__global__ __launch_bounds__(256) void cvt_all(
    const float* __restrict__ q,  const float* __restrict__ wq,
    const float* __restrict__ wk, const float* __restrict__ wv,
    const float* __restrict__ wo,
    unsigned short* __restrict__ q_bf, unsigned short* __restrict__ wqkv,
    unsigned short* __restrict__ wo_f16, float scale_k)
{
    const int NQ = 4096 * 1024, NW = 1024 * 1024;
    int i = (blockIdx.x * 256 + threadIdx.x) * 4;
    const float* src; unsigned short* dst; float sc = 1.0f; int off; bool h16 = false;
    if (i < NQ)               { src = q;  dst = q_bf;          off = i; }
    else if (i < NQ + NW)     { src = wq; dst = wqkv;          off = i - NQ; }
    else if (i < NQ + 2 * NW) { src = wk; dst = wqkv + NW;     off = i - NQ - NW; sc = scale_k; }
    else if (i < NQ + 3 * NW) { src = wv; dst = wqkv + 2 * NW; off = i - NQ - 2 * NW; }
    else                      { src = wo; dst = wo_f16;        off = i - NQ - 3 * NW; h16 = true; }
    float4 v = *(const float4*)(src + off);
    ushort4v o;
    if (h16) {
        o[0] = f2h(v.x); o[1] = f2h(v.y); o[2] = f2h(v.z); o[3] = f2h(v.w);
    } else {
        o[0] = f2bf(v.x * sc); o[1] = f2bf(v.y * sc);
        o[2] = f2bf(v.z * sc); o[3] = f2bf(v.w * sc);
    }
    *(ushort4v*)(dst + off) = o;
}

// ---------------- qkv_gemm: [query]@[Wq;Wk;Wv]^T + bias ----------------
// XCD-chunked block remap (r16, kept: FETCH 40->~25MB). Body = r13.
__global__ __launch_bounds__(256) void qkv_gemm(
    const unsigned short* __restrict__ A,
    const unsigned short* __restrict__ B,
    unsigned short* __restrict__ qkv,
    _Float16* __restrict__ vtg,
    const float* __restrict__ b0, const float* __restrict__ b1, const float* __restrict__ b2,
    float s1)
{
    __shared__ __align__(16) unsigned short As[128 * 64];
    __shared__ __align__(16) unsigned short Bs[128 * 64];

    const int tid  = threadIdx.x;
    const int lane = tid & 63, wave = tid >> 6;
    const int quad = lane >> 4, l15 = lane & 15;
    const int wm = wave >> 1, wn = wave & 1;

    const int lin = blockIdx.x + 24 * blockIdx.y;   // 0..767, x-fastest dispatch
    const int xcd = lin & 7, jj = lin >> 3;         // jj in 0..95
    const int bx = xcd * 3 + (jj >> 5);             // 3 bx-panels per XCD
    const int by = jj & 31;
    const int K = 1024;

    const int srow = lane >> 3;
    const int sp   = lane & 7;
    const int scl  = sp ^ srow;
    const int sw   = l15 & 7;

    f32x4 acc[4][4];
#pragma unroll
    for (int i = 0; i < 4; ++i)
#pragma unroll
        for (int j = 0; j < 4; ++j) acc[i][j] = (f32x4)(0.0f);

    for (int kt = 0; kt < 16; ++kt) {
        __syncthreads();
#pragma unroll
        for (int j = 0; j < 4; ++j) {
            int r0 = wave * 32 + j * 8;
            async16(A + (size_t)(by * 128 + r0 + srow) * K + kt * 64 + scl * 8, &As[r0 * 64]);
            async16(B + (size_t)(bx * 128 + r0 + srow) * K + kt * 64 + scl * 8, &Bs[r0 * 64]);
        }
        __syncthreads();

#pragma unroll
        for (int kh = 0; kh < 2; ++kh) {
            bf16x8 af[4], bfr[4];
#pragma unroll
            for (int mi = 0; mi < 4; ++mi)
                af[mi] = __builtin_bit_cast(bf16x8,
                    *(const ushort8*)&As[(wm * 64 + mi * 16 + l15) * 64 + ((kh * 4 + quad) ^ sw) * 8]);
#pragma unroll
            for (int ni = 0; ni < 4; ++ni)
                bfr[ni] = __builtin_bit_cast(bf16x8,
                    *(const ushort8*)&Bs[(wn * 64 + ni * 16 + l15) * 64 + ((kh * 4 + quad) ^ sw) * 8]);
#pragma unroll
            for (int mi = 0; mi < 4; ++mi)
#pragma unroll
                for (int ni = 0; ni < 4; ++ni)
                    acc[mi][ni] = __builtin_amdgcn_mfma_f32_16x16x32_bf16(af[mi], bfr[ni], acc[mi][ni], 0, 0, 0);
        }
    }

    if (bx < 16) {
#pragma unroll
        for (int ni = 0; ni < 4; ++ni) {
            int n = bx * 128 + wn * 64 + ni * 16 + l15;
            float bias = (n < 1024) ? b0[n] : b1[n - 1024] * s1;
#pragma unroll
            for (int mi = 0; mi < 4; ++mi) {
#pragma unroll
                for (int r = 0; r < 4; ++r) {
                    int m = by * 128 + wm * 64 + mi * 16 + quad * 4 + r;
                    qkv[(size_t)m * 2048 + n] = f2bf(acc[mi][ni][r] + bias);
                }
            }
        }
    } else {
        // V region: token t = mi*16 + quad*4 + r at slot p*8 + (mi&1)*4 + r,
        // p = ((mi>>1)*4+quad)^(hd&7) -> chunk holds tokens in order
        // [32g+4q+0..3, 32g+16+4q+0..3] = concat(pv[2g],pv[2g+1]).
        const int mb = by * 128 + wm * 64;
        const int b  = mb >> 11;
        const int st = (mb & 2047) >> 6;
#pragma unroll
        for (int ni = 0; ni < 4; ++ni) {
            int vf = (bx - 16) * 128 + wn * 64 + ni * 16 + l15;
            int h = vf >> 6, hd = vf & 63;
            float bias = b2[vf];
            _Float16* vrow = vtg + ((size_t)((b * 16 + h) * 64 + hd)) * 2048 + st * 64;
#pragma unroll
            for (int mi = 0; mi < 4; ++mi) {
                int p = ((mi >> 1) * 4 + quad) ^ (l15 & 7);
                f16x4 o;
#pragma unroll
                for (int r = 0; r < 4; ++r) o[r] = (_Float16)(acc[mi][ni][r] + bias);
                *(f16x4*)(vrow + p * 8 + (mi & 1) * 4) = o;
            }
        }
    }
}

// ---------------- out = ctx[4096,1024](f16) @ wo(f16)^T + bo (fp32 out) ----------------
// r17: f16 MFMA (ctx and wo_f16 are f16); structure/XCD-remap = r16.
__global__ __launch_bounds__(256) void out_gemm(
    const _Float16* __restrict__ A,
    const unsigned short* __restrict__ B,
    float* __restrict__ Cout,
    const float* __restrict__ bo)
{
    __shared__ __align__(16) unsigned short As[128 * 64];
    __shared__ __align__(16) unsigned short Bs[64 * 64];

    const int tid  = threadIdx.x;
    const int lane = tid & 63, wave = tid >> 6;
    const int quad = lane >> 4, l15 = lane & 15;
    const int wm = wave >> 1, wn = wave & 1;

    const int lin = blockIdx.x + 16 * blockIdx.y;   // 0..511
    const int xcd = lin & 7, jj = lin >> 3;         // jj in 0..63
    const int bx = xcd * 2 + (jj >> 5);             // 2 bx-panels per XCD
    const int by = jj & 31;
    const int K = 1024;

    const int srow = lane >> 3;
    const int sp   = lane & 7;
    const int scl  = sp ^ srow;
    const int sw   = l15 & 7;

    f32x4 acc[4][2];
#pragma unroll
    for (int i = 0; i < 4; ++i)
#pragma unroll
        for (int j = 0; j < 2; ++j) acc[i][j] = (f32x4)(0.0f);

    for (int kt = 0; kt < 16; ++kt) {
        __syncthreads();
#pragma unroll
        for (int j = 0; j < 4; ++j) {
            int r0 = wave * 32 + j * 8;
            async16(A + (size_t)(by * 128 + r0 + srow) * K + kt * 64 + scl * 8, &As[r0 * 64]);
        }
#pragma unroll
        for (int j = 0; j < 2; ++j) {
            int r0 = wave * 16 + j * 8;
            async16(B + (size_t)(bx * 64 + r0 + srow) * K + kt * 64 + scl * 8, &Bs[r0 * 64]);
        }
        __syncthreads();

#pragma unroll
        for (int kh = 0; kh < 2; ++kh) {
            f16x8 af[4], bfr[2];
#pragma unroll
            for (int mi = 0; mi < 4; ++mi)
                af[mi] = __builtin_bit_cast(f16x8,
                    *(const ushort8*)&As[(wm * 64 + mi * 16 + l15) * 64 + ((kh * 4 + quad) ^ sw) * 8]);
#pragma unroll
            for (int ni = 0; ni < 2; ++ni)
                bfr[ni] = __builtin_bit_cast(f16x8,
                    *(const ushort8*)&Bs[(wn * 32 + ni * 16 + l15) * 64 + ((kh * 4 + quad) ^ sw) * 8]);
#pragma unroll
            for (int mi = 0; mi < 4; ++mi)
#pragma unroll
                for (int ni = 0; ni < 2; ++ni)
                    acc[mi][ni] = __builtin_amdgcn_mfma_f32_16x16x32_f16(af[mi], bfr[ni], acc[mi][ni], 0, 0, 0);
        }
    }

#pragma unroll
    for (int ni = 0; ni < 2; ++ni) {
        int n = bx * 64 + wn * 32 + ni * 16 + l15;
        float bias = bo[n];
#pragma unroll
        for (int mi = 0; mi < 4; ++mi) {
#pragma unroll
            for (int r = 0; r < 4; ++r) {
                int m = by * 128 + wm * 64 + mi * 16 + quad * 4 + r;
                Cout[(size_t)m * 1024 + n] = acc[mi][ni][r] + bias;
            }
        }
    }
}

// ---------------- flash attention: r13 structure + XCD remap + setprio + l-tree ----------------
// KVBLK=256 (4 subtiles per drain+barrier pair), QBLK=128, K=32 PV MFMA.
// r17: s_setprio(1) around the compute phase (T5, m191: +4-7% on attn-like structures
// with independent blocks per CU); l_acc via f32 tree (r14-validated) instead of the
// 8-deep serial fdot2 chain; ctx written as f16 (1-op cvt vs 3-op f2bf).
__global__ __launch_bounds__(256) void attn(const unsigned short* __restrict__ qkv,
                                            const _Float16* __restrict__ vtg,
                                            _Float16* __restrict__ ctx)
{
    __shared__ __align__(16) unsigned short Ks[4 * 64 * 64];
    __shared__ __align__(16) _Float16 Vt[4 * 64 * 64];

    const int tid  = threadIdx.x;
    const int lane = tid & 63, wave = tid >> 6;
    const int quad = lane >> 4, l15 = lane & 15;

    const int lin = blockIdx.x + 16 * blockIdx.y;   // 0..511
    const int xcd = lin & 7, jj = lin >> 3;         // jj in 0..63
    const int bh = xcd * 4 + (jj >> 4);             // 4 heads per XCD
    const int b = bh >> 4, h = bh & 15;
    const int q0 = (jj & 15) * 128;

    const int srow = lane >> 3;
    const int sp   = lane & 7;
    const int scl  = sp ^ srow;
    const int sw   = l15 & 7;

    bf16x8 qf[2][2];
#pragma unroll
    for (int s = 0; s < 2; ++s) {
        int qrow = b * 2048 + q0 + wave * 32 + s * 16 + l15;
#pragma unroll
        for (int kh = 0; kh < 2; ++kh)
            qf[s][kh] = __builtin_bit_cast(bf16x8,
                *(const ushort8*)(qkv + (size_t)qrow * 2048 + h * 64 + kh * 32 + quad * 8));
    }

    f32x4 ot[2][4];
#pragma unroll
    for (int s = 0; s < 2; ++s)
#pragma unroll
        for (int ht = 0; ht < 4; ++ht) ot[s][ht] = (f32x4)(0.0f);
    float l_acc[2] = {0.0f, 0.0f};

    for (int KT = 0; KT < 8; ++KT) {
        __syncthreads();
#pragma unroll
        for (int j = 0; j < 4; ++j) {
            int kt = KT * 4 + j;
#pragma unroll
            for (int i = 0; i < 2; ++i) {
                int row = i * 32 + wave * 8 + srow;
                async16(qkv + (size_t)(b * 2048 + kt * 64 + row) * 2048 + 1024 + h * 64 + scl * 8,
                        &Ks[j * 4096 + (i * 32 + wave * 8) * 64]);
                async16(vtg + (size_t)(bh * 64 + row) * 2048 + kt * 64 + sp * 8,
                        (unsigned short*)&Vt[j * 4096 + (i * 32 + wave * 8) * 64]);
            }
        }
        __syncthreads();

        __builtin_amdgcn_s_setprio(1);
#pragma unroll
        for (int j = 0; j < 4; ++j) {
            const unsigned short* KsJ = &Ks[j * 4096];
            const _Float16*       VtJ = &Vt[j * 4096];

            f16x4 pv[2][4];
#pragma unroll
            for (int mt = 0; mt < 4; ++mt) {
                const unsigned short* kb = &KsJ[(mt * 16 + l15) * 64];
                bf16x8 k0 = __builtin_bit_cast(bf16x8, *(const ushort8*)(kb + (quad ^ sw) * 8));
                bf16x8 k1 = __builtin_bit_cast(bf16x8, *(const ushort8*)(kb + ((quad ^ sw) ^ 4) * 8));
#pragma unroll
                for (int s = 0; s < 2; ++s) {
                    f32x4 s4 = (f32x4)(0.0f);
                    s4 = __builtin_amdgcn_mfma_f32_16x16x32_bf16(k0, qf[s][0], s4, 0, 0, 0);
                    s4 = __builtin_amdgcn_mfma_f32_16x16x32_bf16(k1, qf[s][1], s4, 0, 0, 0);
                    float p0 = __builtin_amdgcn_exp2f(s4[0]);
                    float p1 = __builtin_amdgcn_exp2f(s4[1]);
                    float p2 = __builtin_amdgcn_exp2f(s4[2]);
                    float p3 = __builtin_amdgcn_exp2f(s4[3]);
                    fp16v2 lo = __builtin_amdgcn_cvt_pkrtz(p0, p1);
                    fp16v2 hi = __builtin_amdgcn_cvt_pkrtz(p2, p3);
                    l_acc[s] += (p0 + p1) + (p2 + p3);
                    f16x2 lo2 = __builtin_bit_cast(f16x2, lo);
                    f16x2 hi2 = __builtin_bit_cast(f16x2, hi);
                    pv[s][mt] = __builtin_shufflevector(lo2, hi2, 0, 1, 2, 3);
                }
            }

#pragma unroll
            for (int ht = 0; ht < 4; ++ht) {
                const _Float16* vb = &VtJ[(ht * 16 + l15) * 64];
#pragma unroll
                for (int g = 0; g < 2; ++g) {
                    f16x8 v8 = *(const f16x8*)(vb + (((g * 4 + quad) ^ sw)) * 8);
#pragma unroll
                    for (int s = 0; s < 2; ++s) {
                        f16x8 p8 = __builtin_shufflevector(pv[s][2 * g], pv[s][2 * g + 1],
                                                           0, 1, 2, 3, 4, 5, 6, 7);
                        ot[s][ht] = __builtin_amdgcn_mfma_f32_16x16x32_f16(v8, p8, ot[s][ht], 0, 0, 0);
                    }
                }
            }
        }
        __builtin_amdgcn_s_setprio(0);
    }

#pragma unroll
    for (int s = 0; s < 2; ++s) {
        float l = l_acc[s];
        l += __shfl_xor(l, 16, 64);
        l += __shfl_xor(l, 32, 64);
        float inv = 1.0f / l;
        int qrow = b * 2048 + q0 + wave * 32 + s * 16 + l15;
#pragma unroll
        for (int ht = 0; ht < 4; ++ht) {
            f16x4 o4;
#pragma unroll
            for (int r = 0; r < 4; ++r) o4[r] = (_Float16)(ot[s][ht][r] * inv);
            *(f16x4*)(ctx + (size_t)qrow * 1024 + h * 64 + ht * 16 + quad * 4) = o4;
        }
    }
}

extern "C" void kernel_launch(void* const* d_in, const int* in_sizes, int n_in,
                              void* d_out, int out_size, void* d_ws, size_t ws_size,
                              hipStream_t stream) {
    const float* query = (const float*)d_in[0];
    const float* Wq = (const float*)d_in[1];
    const float* bq = (const float*)d_in[2];
    const float* Wk = (const float*)d_in[3];
    const float* bk = (const float*)d_in[4];
    const float* Wv = (const float*)d_in[5];
    const float* bv = (const float*)d_in[6];
    const float* Wo = (const float*)d_in[7];
    const float* bo = (const float*)d_in[8];

    char* ws = (char*)d_ws;
    unsigned short* q_bf  = (unsigned short*)(ws);                 // 8 MB (dead after qkv_gemm)
    _Float16*       ctx   = (_Float16*)(ws);                       // aliases q_bf (attn writes after q_bf dead)
    unsigned short* wqkv  = (unsigned short*)(ws + 8388608);       // 6 MB
    unsigned short* wo_f  = (unsigned short*)(ws + 14680064);      // 2 MB (f16)
    unsigned short* qkv   = (unsigned short*)(ws + 16777216);      // [4096][2048] bf16 = 16 MB (Q,K only)
    _Float16*       vtg   = (_Float16*)(ws + 33554432);            // [32][64][2048] f16 = 8 MB

    const float SCALE = 0.125f * 1.4426950408889634f;   // (1/sqrt(hd)) * log2(e), folded into K

    cvt_all<<<8192, 256, 0, stream>>>(query, Wq, Wk, Wv, Wo, q_bf, wqkv, wo_f, SCALE);
    qkv_gemm<<<dim3(24, 32), 256, 0, stream>>>(q_bf, wqkv, qkv, vtg, bq, bk, bv, SCALE);
    attn<<<dim3(16, 32), 256, 0, stream>>>(qkv, vtg, ctx);
    out_gemm<<<dim3(16, 32), 256, 0, stream>>>(ctx, wo_f, (float*)d_out, bo);
}

// Round 12
// 189.031 us; speedup vs baseline: 1.0406x; 1.0406x over previous
//
#include <hip/hip_runtime.h>

typedef __attribute__((ext_vector_type(8))) __bf16 bf16x8;
typedef __attribute__((ext_vector_type(8))) unsigned short ushort8;
typedef __attribute__((ext_vector_type(4))) unsigned short ushort4v;
typedef __attribute__((ext_vector_type(4))) float f32x4;
typedef __attribute__((ext_vector_type(2))) _Float16 f16x2;
typedef __attribute__((ext_vector_type(4))) _Float16 f16x4;
typedef __attribute__((ext_vector_type(8))) _Float16 f16x8;
typedef __attribute__((ext_vector_type(2))) __fp16 fp16v2;

__device__ __forceinline__ unsigned short f2bf(float f) {
    union { float f; unsigned int u; } c; c.f = f;
    unsigned int u = c.u;
    u += 0x7fffu + ((u >> 16) & 1u);
    return (unsigned short)(u >> 16);
}

__device__ __forceinline__ unsigned short f2h(float f) {
    _Float16 h = (_Float16)f;
    return __builtin_bit_cast(unsigned short, h);
}

// async global->LDS, 16 B per lane; LDS dest = wave-uniform base + lane*16
__device__ __forceinline__ void async16(const void* g, void* l) {
    __builtin_amdgcn_global_load_lds(
        (const __attribute__((address_space(1))) unsigned int*)g,
        (__attribute__((address_space(3))) unsigned int*)l, 16, 0, 0);
}

// ---------------- fused fp32 -> bf16/f16 conversion for all 5 tensors ----------------
__global__ __launch_bounds__(256) void cvt_all(
    const float* __restrict__ q,  const float* __restrict__ wq,
    const float* __restrict__ wk, const float* __restrict__ wv,
    const float* __restrict__ wo,
    unsigned short* __restrict__ q_bf, unsigned short* __restrict__ wqkv,
    unsigned short* __restrict__ wo_f16, float scale_k)
{
    const int NQ = 4096 * 1024, NW = 1024 * 1024;
    int i = (blockIdx.x * 256 + threadIdx.x) * 4;
    const float* src; unsigned short* dst; float sc = 1.0f; int off; bool h16 = false;
    if (i < NQ)               { src = q;  dst = q_bf;          off = i; }
    else if (i < NQ + NW)     { src = wq; dst = wqkv;          off = i - NQ; }
    else if (i < NQ + 2 * NW) { src = wk; dst = wqkv + NW;     off = i - NQ - NW; sc = scale_k; }
    else if (i < NQ + 3 * NW) { src = wv; dst = wqkv + 2 * NW; off = i - NQ - 2 * NW; }
    else                      { src = wo; dst = wo_f16;        off = i - NQ - 3 * NW; h16 = true; }
    float4 v = *(const float4*)(src + off);
    ushort4v o;
    if (h16) {
        o[0] = f2h(v.x); o[1] = f2h(v.y); o[2] = f2h(v.z); o[3] = f2h(v.w);
    } else {
        o[0] = f2bf(v.x * sc); o[1] = f2bf(v.y * sc);
        o[2] = f2bf(v.z * sc); o[3] = f2bf(v.w * sc);
    }
    *(ushort4v*)(dst + off) = o;
}

// ---------------- qkv_gemm: [query]@[Wq;Wk;Wv]^T + bias ----------------
// r18: 2 BK=64 subtiles staged per drain+barrier pair (r13 regroup, +~2us on attn);
// LDS 64KB, 2 blocks/CU. XCD-chunked remap kept. Indexing/compute body unchanged.
__global__ __launch_bounds__(256) void qkv_gemm(
    const unsigned short* __restrict__ A,
    const unsigned short* __restrict__ B,
    unsigned short* __restrict__ qkv,
    _Float16* __restrict__ vtg,
    const float* __restrict__ b0, const float* __restrict__ b1, const float* __restrict__ b2,
    float s1)
{
    __shared__ __align__(16) unsigned short As[2 * 128 * 64];
    __shared__ __align__(16) unsigned short Bs[2 * 128 * 64];

    const int tid  = threadIdx.x;
    const int lane = tid & 63, wave = tid >> 6;
    const int quad = lane >> 4, l15 = lane & 15;
    const int wm = wave >> 1, wn = wave & 1;

    const int lin = blockIdx.x + 24 * blockIdx.y;   // 0..767, x-fastest dispatch
    const int xcd = lin & 7, jj = lin >> 3;         // jj in 0..95
    const int bx = xcd * 3 + (jj >> 5);             // 3 bx-panels per XCD
    const int by = jj & 31;
    const int K = 1024;

    const int srow = lane >> 3;
    const int sp   = lane & 7;
    const int scl  = sp ^ srow;
    const int sw   = l15 & 7;

    f32x4 acc[4][4];
#pragma unroll
    for (int i = 0; i < 4; ++i)
#pragma unroll
        for (int j = 0; j < 4; ++j) acc[i][j] = (f32x4)(0.0f);

    for (int KT = 0; KT < 8; ++KT) {
        __syncthreads();
#pragma unroll
        for (int t2 = 0; t2 < 2; ++t2) {
            int kt = KT * 2 + t2;
#pragma unroll
            for (int j = 0; j < 4; ++j) {
                int r0 = wave * 32 + j * 8;
                async16(A + (size_t)(by * 128 + r0 + srow) * K + kt * 64 + scl * 8,
                        &As[t2 * 8192 + r0 * 64]);
                async16(B + (size_t)(bx * 128 + r0 + srow) * K + kt * 64 + scl * 8,
                        &Bs[t2 * 8192 + r0 * 64]);
            }
        }
        __syncthreads();

#pragma unroll
        for (int t2 = 0; t2 < 2; ++t2) {
            const unsigned short* AsJ = &As[t2 * 8192];
            const unsigned short* BsJ = &Bs[t2 * 8192];
#pragma unroll
            for (int kh = 0; kh < 2; ++kh) {
                bf16x8 af[4], bfr[4];
#pragma unroll
                for (int mi = 0; mi < 4; ++mi)
                    af[mi] = __builtin_bit_cast(bf16x8,
                        *(const ushort8*)&AsJ[(wm * 64 + mi * 16 + l15) * 64 + ((kh * 4 + quad) ^ sw) * 8]);
#pragma unroll
                for (int ni = 0; ni < 4; ++ni)
                    bfr[ni] = __builtin_bit_cast(bf16x8,
                        *(const ushort8*)&BsJ[(wn * 64 + ni * 16 + l15) * 64 + ((kh * 4 + quad) ^ sw) * 8]);
#pragma unroll
                for (int mi = 0; mi < 4; ++mi)
#pragma unroll
                    for (int ni = 0; ni < 4; ++ni)
                        acc[mi][ni] = __builtin_amdgcn_mfma_f32_16x16x32_bf16(af[mi], bfr[ni], acc[mi][ni], 0, 0, 0);
            }
        }
    }

    if (bx < 16) {
#pragma unroll
        for (int ni = 0; ni < 4; ++ni) {
            int n = bx * 128 + wn * 64 + ni * 16 + l15;
            float bias = (n < 1024) ? b0[n] : b1[n - 1024] * s1;
#pragma unroll
            for (int mi = 0; mi < 4; ++mi) {
#pragma unroll
                for (int r = 0; r < 4; ++r) {
                    int m = by * 128 + wm * 64 + mi * 16 + quad * 4 + r;
                    qkv[(size_t)m * 2048 + n] = f2bf(acc[mi][ni][r] + bias);
                }
            }
        }
    } else {
        // V region: token t = mi*16 + quad*4 + r at slot p*8 + (mi&1)*4 + r,
        // p = ((mi>>1)*4+quad)^(hd&7) -> chunk holds tokens in order
        // [32g+4q+0..3, 32g+16+4q+0..3] = concat(pv[2g],pv[2g+1]).
        const int mb = by * 128 + wm * 64;
        const int b  = mb >> 11;
        const int st = (mb & 2047) >> 6;
#pragma unroll
        for (int ni = 0; ni < 4; ++ni) {
            int vf = (bx - 16) * 128 + wn * 64 + ni * 16 + l15;
            int h = vf >> 6, hd = vf & 63;
            float bias = b2[vf];
            _Float16* vrow = vtg + ((size_t)((b * 16 + h) * 64 + hd)) * 2048 + st * 64;
#pragma unroll
            for (int mi = 0; mi < 4; ++mi) {
                int p = ((mi >> 1) * 4 + quad) ^ (l15 & 7);
                f16x4 o;
#pragma unroll
                for (int r = 0; r < 4; ++r) o[r] = (_Float16)(acc[mi][ni][r] + bias);
                *(f16x4*)(vrow + p * 8 + (mi & 1) * 4) = o;
            }
        }
    }
}

// ---------------- out = ctx[4096,1024](f16) @ wo(f16)^T + bo (fp32 out) ----------------
// r18: 2 subtiles per barrier pair (LDS 48KB); f16 MFMA; XCD remap kept.
__global__ __launch_bounds__(256) void out_gemm(
    const _Float16* __restrict__ A,
    const unsigned short* __restrict__ B,
    float* __restrict__ Cout,
    const float* __restrict__ bo)
{
    __shared__ __align__(16) unsigned short As[2 * 128 * 64];
    __shared__ __align__(16) unsigned short Bs[2 * 64 * 64];

    const int tid  = threadIdx.x;
    const int lane = tid & 63, wave = tid >> 6;
    const int quad = lane >> 4, l15 = lane & 15;
    const int wm = wave >> 1, wn = wave & 1;

    const int lin = blockIdx.x + 16 * blockIdx.y;   // 0..511
    const int xcd = lin & 7, jj = lin >> 3;         // jj in 0..63
    const int bx = xcd * 2 + (jj >> 5);             // 2 bx-panels per XCD
    const int by = jj & 31;
    const int K = 1024;

    const int srow = lane >> 3;
    const int sp   = lane & 7;
    const int scl  = sp ^ srow;
    const int sw   = l15 & 7;

    f32x4 acc[4][2];
#pragma unroll
    for (int i = 0; i < 4; ++i)
#pragma unroll
        for (int j = 0; j < 2; ++j) acc[i][j] = (f32x4)(0.0f);

    for (int KT = 0; KT < 8; ++KT) {
        __syncthreads();
#pragma unroll
        for (int t2 = 0; t2 < 2; ++t2) {
            int kt = KT * 2 + t2;
#pragma unroll
            for (int j = 0; j < 4; ++j) {
                int r0 = wave * 32 + j * 8;
                async16(A + (size_t)(by * 128 + r0 + srow) * K + kt * 64 + scl * 8,
                        &As[t2 * 8192 + r0 * 64]);
            }
#pragma unroll
            for (int j = 0; j < 2; ++j) {
                int r0 = wave * 16 + j * 8;
                async16(B + (size_t)(bx * 64 + r0 + srow) * K + kt * 64 + scl * 8,
                        &Bs[t2 * 4096 + r0 * 64]);
            }
        }
        __syncthreads();

#pragma unroll
        for (int t2 = 0; t2 < 2; ++t2) {
            const unsigned short* AsJ = &As[t2 * 8192];
            const unsigned short* BsJ = &Bs[t2 * 4096];
#pragma unroll
            for (int kh = 0; kh < 2; ++kh) {
                f16x8 af[4], bfr[2];
#pragma unroll
                for (int mi = 0; mi < 4; ++mi)
                    af[mi] = __builtin_bit_cast(f16x8,
                        *(const ushort8*)&AsJ[(wm * 64 + mi * 16 + l15) * 64 + ((kh * 4 + quad) ^ sw) * 8]);
#pragma unroll
                for (int ni = 0; ni < 2; ++ni)
                    bfr[ni] = __builtin_bit_cast(f16x8,
                        *(const ushort8*)&BsJ[(wn * 32 + ni * 16 + l15) * 64 + ((kh * 4 + quad) ^ sw) * 8]);
#pragma unroll
                for (int mi = 0; mi < 4; ++mi)
#pragma unroll
                    for (int ni = 0; ni < 2; ++ni)
                        acc[mi][ni] = __builtin_amdgcn_mfma_f32_16x16x32_f16(af[mi], bfr[ni], acc[mi][ni], 0, 0, 0);
            }
        }
    }

#pragma unroll
    for (int ni = 0; ni < 2; ++ni) {
        int n = bx * 64 + wn * 32 + ni * 16 + l15;
        float bias = bo[n];
#pragma unroll
        for (int mi = 0; mi < 4; ++mi) {
#pragma unroll
            for (int r = 0; r < 4; ++r) {
                int m = by * 128 + wm * 64 + mi * 16 + quad * 4 + r;
                Cout[(size_t)m * 1024 + n] = acc[mi][ni][r] + bias;
            }
        }
    }
}

// ---------------- flash attention: r17 (best measured: 50.3us) unchanged ----------------
// r13 structure + XCD remap + setprio + l-tree + f16 ctx.
__global__ __launch_bounds__(256) void attn(const unsigned short* __restrict__ qkv,
                                            const _Float16* __restrict__ vtg,
                                            _Float16* __restrict__ ctx)
{
    __shared__ __align__(16) unsigned short Ks[4 * 64 * 64];
    __shared__ __align__(16) _Float16 Vt[4 * 64 * 64];

    const int tid  = threadIdx.x;
    const int lane = tid & 63, wave = tid >> 6;
    const int quad = lane >> 4, l15 = lane & 15;

    const int lin = blockIdx.x + 16 * blockIdx.y;   // 0..511
    const int xcd = lin & 7, jj = lin >> 3;         // jj in 0..63
    const int bh = xcd * 4 + (jj >> 4);             // 4 heads per XCD
    const int b = bh >> 4, h = bh & 15;
    const int q0 = (jj & 15) * 128;

    const int srow = lane >> 3;
    const int sp   = lane & 7;
    const int scl  = sp ^ srow;
    const int sw   = l15 & 7;

    bf16x8 qf[2][2];
#pragma unroll
    for (int s = 0; s < 2; ++s) {
        int qrow = b * 2048 + q0 + wave * 32 + s * 16 + l15;
#pragma unroll
        for (int kh = 0; kh < 2; ++kh)
            qf[s][kh] = __builtin_bit_cast(bf16x8,
                *(const ushort8*)(qkv + (size_t)qrow * 2048 + h * 64 + kh * 32 + quad * 8));
    }

    f32x4 ot[2][4];
#pragma unroll
    for (int s = 0; s < 2; ++s)
#pragma unroll
        for (int ht = 0; ht < 4; ++ht) ot[s][ht] = (f32x4)(0.0f);
    float l_acc[2] = {0.0f, 0.0f};

    for (int KT = 0; KT < 8; ++KT) {
        __syncthreads();
#pragma unroll
        for (int j = 0; j < 4; ++j) {
            int kt = KT * 4 + j;
#pragma unroll
            for (int i = 0; i < 2; ++i) {
                int row = i * 32 + wave * 8 + srow;
                async16(qkv + (size_t)(b * 2048 + kt * 64 + row) * 2048 + 1024 + h * 64 + scl * 8,
                        &Ks[j * 4096 + (i * 32 + wave * 8) * 64]);
                async16(vtg + (size_t)(bh * 64 + row) * 2048 + kt * 64 + sp * 8,
                        (unsigned short*)&Vt[j * 4096 + (i * 32 + wave * 8) * 64]);
            }
        }
        __syncthreads();

        __builtin_amdgcn_s_setprio(1);
#pragma unroll
        for (int j = 0; j < 4; ++j) {
            const unsigned short* KsJ = &Ks[j * 4096];
            const _Float16*       VtJ = &Vt[j * 4096];

            f16x4 pv[2][4];
#pragma unroll
            for (int mt = 0; mt < 4; ++mt) {
                const unsigned short* kb = &KsJ[(mt * 16 + l15) * 64];
                bf16x8 k0 = __builtin_bit_cast(bf16x8, *(const ushort8*)(kb + (quad ^ sw) * 8));
                bf16x8 k1 = __builtin_bit_cast(bf16x8, *(const ushort8*)(kb + ((quad ^ sw) ^ 4) * 8));
#pragma unroll
                for (int s = 0; s < 2; ++s) {
                    f32x4 s4 = (f32x4)(0.0f);
                    s4 = __builtin_amdgcn_mfma_f32_16x16x32_bf16(k0, qf[s][0], s4, 0, 0, 0);
                    s4 = __builtin_amdgcn_mfma_f32_16x16x32_bf16(k1, qf[s][1], s4, 0, 0, 0);
                    float p0 = __builtin_amdgcn_exp2f(s4[0]);
                    float p1 = __builtin_amdgcn_exp2f(s4[1]);
                    float p2 = __builtin_amdgcn_exp2f(s4[2]);
                    float p3 = __builtin_amdgcn_exp2f(s4[3]);
                    fp16v2 lo = __builtin_amdgcn_cvt_pkrtz(p0, p1);
                    fp16v2 hi = __builtin_amdgcn_cvt_pkrtz(p2, p3);
                    l_acc[s] += (p0 + p1) + (p2 + p3);
                    f16x2 lo2 = __builtin_bit_cast(f16x2, lo);
                    f16x2 hi2 = __builtin_bit_cast(f16x2, hi);
                    pv[s][mt] = __builtin_shufflevector(lo2, hi2, 0, 1, 2, 3);
                }
            }

#pragma unroll
            for (int ht = 0; ht < 4; ++ht) {
                const _Float16* vb = &VtJ[(ht * 16 + l15) * 64];
#pragma unroll
                for (int g = 0; g < 2; ++g) {
                    f16x8 v8 = *(const f16x8*)(vb + (((g * 4 + quad) ^ sw)) * 8);
#pragma unroll
                    for (int s = 0; s < 2; ++s) {
                        f16x8 p8 = __builtin_shufflevector(pv[s][2 * g], pv[s][2 * g + 1],
                                                           0, 1, 2, 3, 4, 5, 6, 7);
                        ot[s][ht] = __builtin_amdgcn_mfma_f32_16x16x32_f16(v8, p8, ot[s][ht], 0, 0, 0);
                    }
                }
            }
        }
        __builtin_amdgcn_s_setprio(0);
    }

#pragma unroll
    for (int s = 0; s < 2; ++s) {
        float l = l_acc[s];
        l += __shfl_xor(l, 16, 64);
        l += __shfl_xor(l, 32, 64);
        float inv = 1.0f / l;
        int qrow = b * 2048 + q0 + wave * 32 + s * 16 + l15;
#pragma unroll
        for (int ht = 0; ht < 4; ++ht) {
            f16x4 o4;
#pragma unroll
            for (int r = 0; r < 4; ++r) o4[r] = (_Float16)(ot[s][ht][r] * inv);
            *(f16x4*)(ctx + (size_t)qrow * 1024 + h * 64 + ht * 16 + quad * 4) = o4;
        }
    }
}

extern "C" void kernel_launch(void* const* d_in, const int* in_sizes, int n_in,
                              void* d_out, int out_size, void* d_ws, size_t ws_size,
                              hipStream_t stream) {
    const float* query = (const float*)d_in[0];
    const float* Wq = (const float*)d_in[1];
    const float* bq = (const float*)d_in[2];
    const float* Wk = (const float*)d_in[3];
    const float* bk = (const float*)d_in[4];
    const float* Wv = (const float*)d_in[5];
    const float* bv = (const float*)d_in[6];
    const float* Wo = (const float*)d_in[7];
    const float* bo = (const float*)d_in[8];

    char* ws = (char*)d_ws;
    unsigned short* q_bf  = (unsigned short*)(ws);                 // 8 MB (dead after qkv_gemm)
    _Float16*       ctx   = (_Float16*)(ws);                       // aliases q_bf (attn writes after q_bf dead)
    unsigned short* wqkv  = (unsigned short*)(ws + 8388608);       // 6 MB
    unsigned short* wo_f  = (unsigned short*)(ws + 14680064);      // 2 MB (f16)
    unsigned short* qkv   = (unsigned short*)(ws + 16777216);      // [4096][2048] bf16 = 16 MB (Q,K only)
    _Float16*       vtg   = (_Float16*)(ws + 33554432);            // [32][64][2048] f16 = 8 MB

    const float SCALE = 0.125f * 1.4426950408889634f;   // (1/sqrt(hd)) * log2(e), folded into K

    cvt_all<<<8192, 256, 0, stream>>>(query, Wq, Wk, Wv, Wo, q_bf, wqkv, wo_f, SCALE);
    qkv_gemm<<<dim3(24, 32), 256, 0, stream>>>(q_bf, wqkv, qkv, vtg, bq, bk, bv, SCALE);
    attn<<<dim3(16, 32), 256, 0, stream>>>(qkv, vtg, ctx);
    out_gemm<<<dim3(16, 32), 256, 0, stream>>>(ctx, wo_f, (float*)d_out, bo);
}

// Round 13
// 185.006 us; speedup vs baseline: 1.0633x; 1.0218x over previous
//
#include <hip/hip_runtime.h>

typedef __attribute__((ext_vector_type(8))) __bf16 bf16x8;
typedef __attribute__((ext_vector_type(8))) unsigned short ushort8;
typedef __attribute__((ext_vector_type(4))) unsigned short ushort4v;
typedef __attribute__((ext_vector_type(4))) float f32x4;
typedef __attribute__((ext_vector_type(2))) _Float16 f16x2;
typedef __attribute__((ext_vector_type(4))) _Float16 f16x4;
typedef __attribute__((ext_vector_type(8))) _Float16 f16x8;
typedef __attribute__((ext_vector_type(2))) __fp16 fp16v2;

__device__ __forceinline__ unsigned short f2bf(float f) {
    union { float f; unsigned int u; } c; c.f = f;
    unsigned int u = c.u;
    u += 0x7fffu + ((u >> 16) & 1u);
    return (unsigned short)(u >> 16);
}

__device__ __forceinline__ unsigned short f2h(float f) {
    _Float16 h = (_Float16)f;
    return __builtin_bit_cast(unsigned short, h);
}

// async global->LDS, 16 B per lane; LDS dest = wave-uniform base + lane*16
__device__ __forceinline__ void async16(const void* g, void* l) {
    __builtin_amdgcn_global_load_lds(
        (const __attribute__((address_space(1))) unsigned int*)g,
        (__attribute__((address_space(3))) unsigned int*)l, 16, 0, 0);
}

// ---------------- fused fp32 -> bf16/f16 conversion for all 5 tensors ----------------
__global__ __launch_bounds__(256) void cvt_all(
    const float* __restrict__ q,  const float* __restrict__ wq,
    const float* __restrict__ wk, const float* __restrict__ wv,
    const float* __restrict__ wo,
    unsigned short* __restrict__ q_bf, unsigned short* __restrict__ wqkv,
    unsigned short* __restrict__ wo_f16, float scale_k)
{
    const int NQ = 4096 * 1024, NW = 1024 * 1024;
    int i = (blockIdx.x * 256 + threadIdx.x) * 4;
    const float* src; unsigned short* dst; float sc = 1.0f; int off; bool h16 = false;
    if (i < NQ)               { src = q;  dst = q_bf;          off = i; }
    else if (i < NQ + NW)     { src = wq; dst = wqkv;          off = i - NQ; }
    else if (i < NQ + 2 * NW) { src = wk; dst = wqkv + NW;     off = i - NQ - NW; sc = scale_k; }
    else if (i < NQ + 3 * NW) { src = wv; dst = wqkv + 2 * NW; off = i - NQ - 2 * NW; }
    else                      { src = wo; dst = wo_f16;        off = i - NQ - 3 * NW; h16 = true; }
    float4 v = *(const float4*)(src + off);
    ushort4v o;
    if (h16) {
        o[0] = f2h(v.x); o[1] = f2h(v.y); o[2] = f2h(v.z); o[3] = f2h(v.w);
    } else {
        o[0] = f2bf(v.x * sc); o[1] = f2bf(v.y * sc);
        o[2] = f2bf(v.z * sc); o[3] = f2bf(v.w * sc);
    }
    *(ushort4v*)(dst + off) = o;
}

// ---------------- qkv_gemm: [query]@[Wq;Wk;Wv]^T + bias ----------------
// r19: 2D XCD chunking — each XCD owns a 12bx x 8by sub-grid (2x4 tiling of 24x32).
// Per-XCD unique panels: 12 B + 8 A = 5MB (vs r16's 1-D 3bx x 32by = 8.75MB ->
// measured 68MB FETCH). by-fastest iteration inside the chunk. Body = r18
// (2 BK=64 subtiles per drain+barrier pair, 64KB LDS).
__global__ __launch_bounds__(256) void qkv_gemm(
    const unsigned short* __restrict__ A,
    const unsigned short* __restrict__ B,
    unsigned short* __restrict__ qkv,
    _Float16* __restrict__ vtg,
    const float* __restrict__ b0, const float* __restrict__ b1, const float* __restrict__ b2,
    float s1)
{
    __shared__ __align__(16) unsigned short As[2 * 128 * 64];
    __shared__ __align__(16) unsigned short Bs[2 * 128 * 64];

    const int tid  = threadIdx.x;
    const int lane = tid & 63, wave = tid >> 6;
    const int quad = lane >> 4, l15 = lane & 15;
    const int wm = wave >> 1, wn = wave & 1;

    const int lin = blockIdx.x + 24 * blockIdx.y;   // 0..767, x-fastest dispatch
    const int xcd = lin & 7, jj = lin >> 3;         // jj in 0..95
    const int gx = xcd & 1, gy = xcd >> 1;          // 2 x 4 chunk grid
    const int bx = gx * 12 + (jj >> 3);             // 12 bx-panels per XCD
    const int by = gy * 8 + (jj & 7);               // 8 by-panels per XCD
    const int K = 1024;

    const int srow = lane >> 3;
    const int sp   = lane & 7;
    const int scl  = sp ^ srow;
    const int sw   = l15 & 7;

    f32x4 acc[4][4];
#pragma unroll
    for (int i = 0; i < 4; ++i)
#pragma unroll
        for (int j = 0; j < 4; ++j) acc[i][j] = (f32x4)(0.0f);

    for (int KT = 0; KT < 8; ++KT) {
        __syncthreads();
#pragma unroll
        for (int t2 = 0; t2 < 2; ++t2) {
            int kt = KT * 2 + t2;
#pragma unroll
            for (int j = 0; j < 4; ++j) {
                int r0 = wave * 32 + j * 8;
                async16(A + (size_t)(by * 128 + r0 + srow) * K + kt * 64 + scl * 8,
                        &As[t2 * 8192 + r0 * 64]);
                async16(B + (size_t)(bx * 128 + r0 + srow) * K + kt * 64 + scl * 8,
                        &Bs[t2 * 8192 + r0 * 64]);
            }
        }
        __syncthreads();

#pragma unroll
        for (int t2 = 0; t2 < 2; ++t2) {
            const unsigned short* AsJ = &As[t2 * 8192];
            const unsigned short* BsJ = &Bs[t2 * 8192];
#pragma unroll
            for (int kh = 0; kh < 2; ++kh) {
                bf16x8 af[4], bfr[4];
#pragma unroll
                for (int mi = 0; mi < 4; ++mi)
                    af[mi] = __builtin_bit_cast(bf16x8,
                        *(const ushort8*)&AsJ[(wm * 64 + mi * 16 + l15) * 64 + ((kh * 4 + quad) ^ sw) * 8]);
#pragma unroll
                for (int ni = 0; ni < 4; ++ni)
                    bfr[ni] = __builtin_bit_cast(bf16x8,
                        *(const ushort8*)&BsJ[(wn * 64 + ni * 16 + l15) * 64 + ((kh * 4 + quad) ^ sw) * 8]);
#pragma unroll
                for (int mi = 0; mi < 4; ++mi)
#pragma unroll
                    for (int ni = 0; ni < 4; ++ni)
                        acc[mi][ni] = __builtin_amdgcn_mfma_f32_16x16x32_bf16(af[mi], bfr[ni], acc[mi][ni], 0, 0, 0);
            }
        }
    }

    if (bx < 16) {
#pragma unroll
        for (int ni = 0; ni < 4; ++ni) {
            int n = bx * 128 + wn * 64 + ni * 16 + l15;
            float bias = (n < 1024) ? b0[n] : b1[n - 1024] * s1;
#pragma unroll
            for (int mi = 0; mi < 4; ++mi) {
#pragma unroll
                for (int r = 0; r < 4; ++r) {
                    int m = by * 128 + wm * 64 + mi * 16 + quad * 4 + r;
                    qkv[(size_t)m * 2048 + n] = f2bf(acc[mi][ni][r] + bias);
                }
            }
        }
    } else {
        // V region: token t = mi*16 + quad*4 + r at slot p*8 + (mi&1)*4 + r,
        // p = ((mi>>1)*4+quad)^(hd&7) -> chunk holds tokens in order
        // [32g+4q+0..3, 32g+16+4q+0..3] = concat(pv[2g],pv[2g+1]).
        const int mb = by * 128 + wm * 64;
        const int b  = mb >> 11;
        const int st = (mb & 2047) >> 6;
#pragma unroll
        for (int ni = 0; ni < 4; ++ni) {
            int vf = (bx - 16) * 128 + wn * 64 + ni * 16 + l15;
            int h = vf >> 6, hd = vf & 63;
            float bias = b2[vf];
            _Float16* vrow = vtg + ((size_t)((b * 16 + h) * 64 + hd)) * 2048 + st * 64;
#pragma unroll
            for (int mi = 0; mi < 4; ++mi) {
                int p = ((mi >> 1) * 4 + quad) ^ (l15 & 7);
                f16x4 o;
#pragma unroll
                for (int r = 0; r < 4; ++r) o[r] = (_Float16)(acc[mi][ni][r] + bias);
                *(f16x4*)(vrow + p * 8 + (mi & 1) * 4) = o;
            }
        }
    }
}

// ---------------- out = ctx[4096,1024](f16) @ wo(f16)^T + bo (fp32 out) ----------------
// r19: 2D XCD chunking — 8bx x 8by per XCD (2x4 tiling of 16x32). Body = r18.
__global__ __launch_bounds__(256) void out_gemm(
    const _Float16* __restrict__ A,
    const unsigned short* __restrict__ B,
    float* __restrict__ Cout,
    const float* __restrict__ bo)
{
    __shared__ __align__(16) unsigned short As[2 * 128 * 64];
    __shared__ __align__(16) unsigned short Bs[2 * 64 * 64];

    const int tid  = threadIdx.x;
    const int lane = tid & 63, wave = tid >> 6;
    const int quad = lane >> 4, l15 = lane & 15;
    const int wm = wave >> 1, wn = wave & 1;

    const int lin = blockIdx.x + 16 * blockIdx.y;   // 0..511
    const int xcd = lin & 7, jj = lin >> 3;         // jj in 0..63
    const int gx = xcd & 1, gy = xcd >> 1;          // 2 x 4 chunk grid
    const int bx = gx * 8 + (jj >> 3);              // 8 bx-panels per XCD
    const int by = gy * 8 + (jj & 7);               // 8 by-panels per XCD
    const int K = 1024;

    const int srow = lane >> 3;
    const int sp   = lane & 7;
    const int scl  = sp ^ srow;
    const int sw   = l15 & 7;

    f32x4 acc[4][2];
#pragma unroll
    for (int i = 0; i < 4; ++i)
#pragma unroll
        for (int j = 0; j < 2; ++j) acc[i][j] = (f32x4)(0.0f);

    for (int KT = 0; KT < 8; ++KT) {
        __syncthreads();
#pragma unroll
        for (int t2 = 0; t2 < 2; ++t2) {
            int kt = KT * 2 + t2;
#pragma unroll
            for (int j = 0; j < 4; ++j) {
                int r0 = wave * 32 + j * 8;
                async16(A + (size_t)(by * 128 + r0 + srow) * K + kt * 64 + scl * 8,
                        &As[t2 * 8192 + r0 * 64]);
            }
#pragma unroll
            for (int j = 0; j < 2; ++j) {
                int r0 = wave * 16 + j * 8;
                async16(B + (size_t)(bx * 64 + r0 + srow) * K + kt * 64 + scl * 8,
                        &Bs[t2 * 4096 + r0 * 64]);
            }
        }
        __syncthreads();

#pragma unroll
        for (int t2 = 0; t2 < 2; ++t2) {
            const unsigned short* AsJ = &As[t2 * 8192];
            const unsigned short* BsJ = &Bs[t2 * 4096];
#pragma unroll
            for (int kh = 0; kh < 2; ++kh) {
                f16x8 af[4], bfr[2];
#pragma unroll
                for (int mi = 0; mi < 4; ++mi)
                    af[mi] = __builtin_bit_cast(f16x8,
                        *(const ushort8*)&AsJ[(wm * 64 + mi * 16 + l15) * 64 + ((kh * 4 + quad) ^ sw) * 8]);
#pragma unroll
                for (int ni = 0; ni < 2; ++ni)
                    bfr[ni] = __builtin_bit_cast(f16x8,
                        *(const ushort8*)&BsJ[(wn * 32 + ni * 16 + l15) * 64 + ((kh * 4 + quad) ^ sw) * 8]);
#pragma unroll
                for (int mi = 0; mi < 4; ++mi)
#pragma unroll
                    for (int ni = 0; ni < 2; ++ni)
                        acc[mi][ni] = __builtin_amdgcn_mfma_f32_16x16x32_f16(af[mi], bfr[ni], acc[mi][ni], 0, 0, 0);
            }
        }
    }

#pragma unroll
    for (int ni = 0; ni < 2; ++ni) {
        int n = bx * 64 + wn * 32 + ni * 16 + l15;
        float bias = bo[n];
#pragma unroll
        for (int mi = 0; mi < 4; ++mi) {
#pragma unroll
            for (int r = 0; r < 4; ++r) {
                int m = by * 128 + wm * 64 + mi * 16 + quad * 4 + r;
                Cout[(size_t)m * 1024 + n] = acc[mi][ni][r] + bias;
            }
        }
    }
}

// ---------------- flash attention: r17 (best measured: 50.3us) unchanged ----------------
// r13 structure + XCD remap + setprio + l-tree + f16 ctx. (r18 measured 58.8 with
// identical source — clock/codegen variance band is 50-59us.)
__global__ __launch_bounds__(256) void attn(const unsigned short* __restrict__ qkv,
                                            const _Float16* __restrict__ vtg,
                                            _Float16* __restrict__ ctx)
{
    __shared__ __align__(16) unsigned short Ks[4 * 64 * 64];
    __shared__ __align__(16) _Float16 Vt[4 * 64 * 64];

    const int tid  = threadIdx.x;
    const int lane = tid & 63, wave = tid >> 6;
    const int quad = lane >> 4, l15 = lane & 15;

    const int lin = blockIdx.x + 16 * blockIdx.y;   // 0..511
    const int xcd = lin & 7, jj = lin >> 3;         // jj in 0..63
    const int bh = xcd * 4 + (jj >> 4);             // 4 heads per XCD
    const int b = bh >> 4, h = bh & 15;
    const int q0 = (jj & 15) * 128;

    const int srow = lane >> 3;
    const int sp   = lane & 7;
    const int scl  = sp ^ srow;
    const int sw   = l15 & 7;

    bf16x8 qf[2][2];
#pragma unroll
    for (int s = 0; s < 2; ++s) {
        int qrow = b * 2048 + q0 + wave * 32 + s * 16 + l15;
#pragma unroll
        for (int kh = 0; kh < 2; ++kh)
            qf[s][kh] = __builtin_bit_cast(bf16x8,
                *(const ushort8*)(qkv + (size_t)qrow * 2048 + h * 64 + kh * 32 + quad * 8));
    }

    f32x4 ot[2][4];
#pragma unroll
    for (int s = 0; s < 2; ++s)
#pragma unroll
        for (int ht = 0; ht < 4; ++ht) ot[s][ht] = (f32x4)(0.0f);
    float l_acc[2] = {0.0f, 0.0f};

    for (int KT = 0; KT < 8; ++KT) {
        __syncthreads();
#pragma unroll
        for (int j = 0; j < 4; ++j) {
            int kt = KT * 4 + j;
#pragma unroll
            for (int i = 0; i < 2; ++i) {
                int row = i * 32 + wave * 8 + srow;
                async16(qkv + (size_t)(b * 2048 + kt * 64 + row) * 2048 + 1024 + h * 64 + scl * 8,
                        &Ks[j * 4096 + (i * 32 + wave * 8) * 64]);
                async16(vtg + (size_t)(bh * 64 + row) * 2048 + kt * 64 + sp * 8,
                        (unsigned short*)&Vt[j * 4096 + (i * 32 + wave * 8) * 64]);
            }
        }
        __syncthreads();

        __builtin_amdgcn_s_setprio(1);
#pragma unroll
        for (int j = 0; j < 4; ++j) {
            const unsigned short* KsJ = &Ks[j * 4096];
            const _Float16*       VtJ = &Vt[j * 4096];

            f16x4 pv[2][4];
#pragma unroll
            for (int mt = 0; mt < 4; ++mt) {
                const unsigned short* kb = &KsJ[(mt * 16 + l15) * 64];
                bf16x8 k0 = __builtin_bit_cast(bf16x8, *(const ushort8*)(kb + (quad ^ sw) * 8));
                bf16x8 k1 = __builtin_bit_cast(bf16x8, *(const ushort8*)(kb + ((quad ^ sw) ^ 4) * 8));
#pragma unroll
                for (int s = 0; s < 2; ++s) {
                    f32x4 s4 = (f32x4)(0.0f);
                    s4 = __builtin_amdgcn_mfma_f32_16x16x32_bf16(k0, qf[s][0], s4, 0, 0, 0);
                    s4 = __builtin_amdgcn_mfma_f32_16x16x32_bf16(k1, qf[s][1], s4, 0, 0, 0);
                    float p0 = __builtin_amdgcn_exp2f(s4[0]);
                    float p1 = __builtin_amdgcn_exp2f(s4[1]);
                    float p2 = __builtin_amdgcn_exp2f(s4[2]);
                    float p3 = __builtin_amdgcn_exp2f(s4[3]);
                    fp16v2 lo = __builtin_amdgcn_cvt_pkrtz(p0, p1);
                    fp16v2 hi = __builtin_amdgcn_cvt_pkrtz(p2, p3);
                    l_acc[s] += (p0 + p1) + (p2 + p3);
                    f16x2 lo2 = __builtin_bit_cast(f16x2, lo);
                    f16x2 hi2 = __builtin_bit_cast(f16x2, hi);
                    pv[s][mt] = __builtin_shufflevector(lo2, hi2, 0, 1, 2, 3);
                }
            }

#pragma unroll
            for (int ht = 0; ht < 4; ++ht) {
                const _Float16* vb = &VtJ[(ht * 16 + l15) * 64];
#pragma unroll
                for (int g = 0; g < 2; ++g) {
                    f16x8 v8 = *(const f16x8*)(vb + (((g * 4 + quad) ^ sw)) * 8);
#pragma unroll
                    for (int s = 0; s < 2; ++s) {
                        f16x8 p8 = __builtin_shufflevector(pv[s][2 * g], pv[s][2 * g + 1],
                                                           0, 1, 2, 3, 4, 5, 6, 7);
                        ot[s][ht] = __builtin_amdgcn_mfma_f32_16x16x32_f16(v8, p8, ot[s][ht], 0, 0, 0);
                    }
                }
            }
        }
        __builtin_amdgcn_s_setprio(0);
    }

#pragma unroll
    for (int s = 0; s < 2; ++s) {
        float l = l_acc[s];
        l += __shfl_xor(l, 16, 64);
        l += __shfl_xor(l, 32, 64);
        float inv = 1.0f / l;
        int qrow = b * 2048 + q0 + wave * 32 + s * 16 + l15;
#pragma unroll
        for (int ht = 0; ht < 4; ++ht) {
            f16x4 o4;
#pragma unroll
            for (int r = 0; r < 4; ++r) o4[r] = (_Float16)(ot[s][ht][r] * inv);
            *(f16x4*)(ctx + (size_t)qrow * 1024 + h * 64 + ht * 16 + quad * 4) = o4;
        }
    }
}

extern "C" void kernel_launch(void* const* d_in, const int* in_sizes, int n_in,
                              void* d_out, int out_size, void* d_ws, size_t ws_size,
                              hipStream_t stream) {
    const float* query = (const float*)d_in[0];
    const float* Wq = (const float*)d_in[1];
    const float* bq = (const float*)d_in[2];
    const float* Wk = (const float*)d_in[3];
    const float* bk = (const float*)d_in[4];
    const float* Wv = (const float*)d_in[5];
    const float* bv = (const float*)d_in[6];
    const float* Wo = (const float*)d_in[7];
    const float* bo = (const float*)d_in[8];

    char* ws = (char*)d_ws;
    unsigned short* q_bf  = (unsigned short*)(ws);                 // 8 MB (dead after qkv_gemm)
    _Float16*       ctx   = (_Float16*)(ws);                       // aliases q_bf (attn writes after q_bf dead)
    unsigned short* wqkv  = (unsigned short*)(ws + 8388608);       // 6 MB
    unsigned short* wo_f  = (unsigned short*)(ws + 14680064);      // 2 MB (f16)
    unsigned short* qkv   = (unsigned short*)(ws + 16777216);      // [4096][2048] bf16 = 16 MB (Q,K only)
    _Float16*       vtg   = (_Float16*)(ws + 33554432);            // [32][64][2048] f16 = 8 MB

    const float SCALE = 0.125f * 1.4426950408889634f;   // (1/sqrt(hd)) * log2(e), folded into K

    cvt_all<<<8192, 256, 0, stream>>>(query, Wq, Wk, Wv, Wo, q_bf, wqkv, wo_f, SCALE);
    qkv_gemm<<<dim3(24, 32), 256, 0, stream>>>(q_bf, wqkv, qkv, vtg, bq, bk, bv, SCALE);
    attn<<<dim3(16, 32), 256, 0, stream>>>(qkv, vtg, ctx);
    out_gemm<<<dim3(16, 32), 256, 0, stream>>>(ctx, wo_f, (float*)d_out, bo);
}

// Round 14
// 182.422 us; speedup vs baseline: 1.0783x; 1.0142x over previous
//
#include <hip/hip_runtime.h>

typedef __attribute__((ext_vector_type(8))) __bf16 bf16x8;
typedef __attribute__((ext_vector_type(8))) unsigned short ushort8;
typedef __attribute__((ext_vector_type(4))) unsigned short ushort4v;
typedef __attribute__((ext_vector_type(4))) float f32x4;
typedef __attribute__((ext_vector_type(2))) _Float16 f16x2;
typedef __attribute__((ext_vector_type(4))) _Float16 f16x4;
typedef __attribute__((ext_vector_type(8))) _Float16 f16x8;
typedef __attribute__((ext_vector_type(2))) __fp16 fp16v2;

__device__ __forceinline__ unsigned short f2bf(float f) {
    union { float f; unsigned int u; } c; c.f = f;
    unsigned int u = c.u;
    u += 0x7fffu + ((u >> 16) & 1u);
    return (unsigned short)(u >> 16);
}

__device__ __forceinline__ unsigned short f2h(float f) {
    _Float16 h = (_Float16)f;
    return __builtin_bit_cast(unsigned short, h);
}

// async global->LDS, 16 B per lane; LDS dest = wave-uniform base + lane*16
__device__ __forceinline__ void async16(const void* g, void* l) {
    __builtin_amdgcn_global_load_lds(
        (const __attribute__((address_space(1))) unsigned int*)g,
        (__attribute__((address_space(3))) unsigned int*)l, 16, 0, 0);
}

// ---------------- fused fp32 -> bf16/f16 conversion for all 5 tensors ----------------
__global__ __launch_bounds__(256) void cvt_all(
    const float* __restrict__ q,  const float* __restrict__ wq,
    const float* __restrict__ wk, const float* __restrict__ wv,
    const float* __restrict__ wo,
    unsigned short* __restrict__ q_bf, unsigned short* __restrict__ wqkv,
    unsigned short* __restrict__ wo_f16, float scale_k)
{
    const int NQ = 4096 * 1024, NW = 1024 * 1024;
    int i = (blockIdx.x * 256 + threadIdx.x) * 4;
    const float* src; unsigned short* dst; float sc = 1.0f; int off; bool h16 = false;
    if (i < NQ)               { src = q;  dst = q_bf;          off = i; }
    else if (i < NQ + NW)     { src = wq; dst = wqkv;          off = i - NQ; }
    else if (i < NQ + 2 * NW) { src = wk; dst = wqkv + NW;     off = i - NQ - NW; sc = scale_k; }
    else if (i < NQ + 3 * NW) { src = wv; dst = wqkv + 2 * NW; off = i - NQ - 2 * NW; }
    else                      { src = wo; dst = wo_f16;        off = i - NQ - 3 * NW; h16 = true; }
    float4 v = *(const float4*)(src + off);
    ushort4v o;
    if (h16) {
        o[0] = f2h(v.x); o[1] = f2h(v.y); o[2] = f2h(v.z); o[3] = f2h(v.w);
    } else {
        o[0] = f2bf(v.x * sc); o[1] = f2bf(v.y * sc);
        o[2] = f2bf(v.z * sc); o[3] = f2bf(v.w * sc);
    }
    *(ushort4v*)(dst + off) = o;
}

// ---------------- qkv_gemm: [query]@[Wq;Wk;Wv]^T + bias ----------------
// r19 (kept): 2D XCD chunking — each XCD owns a 12bx x 8by sub-grid (2x4 tiling of
// 24x32, per-XCD fill 5MB). Body = r18 (2 BK=64 subtiles per drain+barrier, 64KB LDS).
__global__ __launch_bounds__(256) void qkv_gemm(
    const unsigned short* __restrict__ A,
    const unsigned short* __restrict__ B,
    unsigned short* __restrict__ qkv,
    _Float16* __restrict__ vtg,
    const float* __restrict__ b0, const float* __restrict__ b1, const float* __restrict__ b2,
    float s1)
{
    __shared__ __align__(16) unsigned short As[2 * 128 * 64];
    __shared__ __align__(16) unsigned short Bs[2 * 128 * 64];

    const int tid  = threadIdx.x;
    const int lane = tid & 63, wave = tid >> 6;
    const int quad = lane >> 4, l15 = lane & 15;
    const int wm = wave >> 1, wn = wave & 1;

    const int lin = blockIdx.x + 24 * blockIdx.y;   // 0..767, x-fastest dispatch
    const int xcd = lin & 7, jj = lin >> 3;         // jj in 0..95
    const int gx = xcd & 1, gy = xcd >> 1;          // 2 x 4 chunk grid
    const int bx = gx * 12 + (jj >> 3);             // 12 bx-panels per XCD
    const int by = gy * 8 + (jj & 7);               // 8 by-panels per XCD
    const int K = 1024;

    const int srow = lane >> 3;
    const int sp   = lane & 7;
    const int scl  = sp ^ srow;
    const int sw   = l15 & 7;

    f32x4 acc[4][4];
#pragma unroll
    for (int i = 0; i < 4; ++i)
#pragma unroll
        for (int j = 0; j < 4; ++j) acc[i][j] = (f32x4)(0.0f);

    for (int KT = 0; KT < 8; ++KT) {
        __syncthreads();
#pragma unroll
        for (int t2 = 0; t2 < 2; ++t2) {
            int kt = KT * 2 + t2;
#pragma unroll
            for (int j = 0; j < 4; ++j) {
                int r0 = wave * 32 + j * 8;
                async16(A + (size_t)(by * 128 + r0 + srow) * K + kt * 64 + scl * 8,
                        &As[t2 * 8192 + r0 * 64]);
                async16(B + (size_t)(bx * 128 + r0 + srow) * K + kt * 64 + scl * 8,
                        &Bs[t2 * 8192 + r0 * 64]);
            }
        }
        __syncthreads();

#pragma unroll
        for (int t2 = 0; t2 < 2; ++t2) {
            const unsigned short* AsJ = &As[t2 * 8192];
            const unsigned short* BsJ = &Bs[t2 * 8192];
#pragma unroll
            for (int kh = 0; kh < 2; ++kh) {
                bf16x8 af[4], bfr[4];
#pragma unroll
                for (int mi = 0; mi < 4; ++mi)
                    af[mi] = __builtin_bit_cast(bf16x8,
                        *(const ushort8*)&AsJ[(wm * 64 + mi * 16 + l15) * 64 + ((kh * 4 + quad) ^ sw) * 8]);
#pragma unroll
                for (int ni = 0; ni < 4; ++ni)
                    bfr[ni] = __builtin_bit_cast(bf16x8,
                        *(const ushort8*)&BsJ[(wn * 64 + ni * 16 + l15) * 64 + ((kh * 4 + quad) ^ sw) * 8]);
#pragma unroll
                for (int mi = 0; mi < 4; ++mi)
#pragma unroll
                    for (int ni = 0; ni < 4; ++ni)
                        acc[mi][ni] = __builtin_amdgcn_mfma_f32_16x16x32_bf16(af[mi], bfr[ni], acc[mi][ni], 0, 0, 0);
            }
        }
    }

    if (bx < 16) {
#pragma unroll
        for (int ni = 0; ni < 4; ++ni) {
            int n = bx * 128 + wn * 64 + ni * 16 + l15;
            float bias = (n < 1024) ? b0[n] : b1[n - 1024] * s1;
#pragma unroll
            for (int mi = 0; mi < 4; ++mi) {
#pragma unroll
                for (int r = 0; r < 4; ++r) {
                    int m = by * 128 + wm * 64 + mi * 16 + quad * 4 + r;
                    qkv[(size_t)m * 2048 + n] = f2bf(acc[mi][ni][r] + bias);
                }
            }
        }
    } else {
        // V region: token t = mi*16 + quad*4 + r at slot p*8 + (mi&1)*4 + r,
        // p = ((mi>>1)*4+quad)^(hd&7) -> chunk holds tokens in order
        // [32g+4q+0..3, 32g+16+4q+0..3] = concat(pv[2g],pv[2g+1]).
        const int mb = by * 128 + wm * 64;
        const int b  = mb >> 11;
        const int st = (mb & 2047) >> 6;
#pragma unroll
        for (int ni = 0; ni < 4; ++ni) {
            int vf = (bx - 16) * 128 + wn * 64 + ni * 16 + l15;
            int h = vf >> 6, hd = vf & 63;
            float bias = b2[vf];
            _Float16* vrow = vtg + ((size_t)((b * 16 + h) * 64 + hd)) * 2048 + st * 64;
#pragma unroll
            for (int mi = 0; mi < 4; ++mi) {
                int p = ((mi >> 1) * 4 + quad) ^ (l15 & 7);
                f16x4 o;
#pragma unroll
                for (int r = 0; r < 4; ++r) o[r] = (_Float16)(acc[mi][ni][r] + bias);
                *(f16x4*)(vrow + p * 8 + (mi & 1) * 4) = o;
            }
        }
    }
}

// ---------------- out = ctx[4096,1024](f16) @ wo(f16)^T + bo (fp32 out) ----------------
// r19 (kept): 2D XCD chunking — 8bx x 8by per XCD (4MB fill, L2-fits). Body = r18.
__global__ __launch_bounds__(256) void out_gemm(
    const _Float16* __restrict__ A,
    const unsigned short* __restrict__ B,
    float* __restrict__ Cout,
    const float* __restrict__ bo)
{
    __shared__ __align__(16) unsigned short As[2 * 128 * 64];
    __shared__ __align__(16) unsigned short Bs[2 * 64 * 64];

    const int tid  = threadIdx.x;
    const int lane = tid & 63, wave = tid >> 6;
    const int quad = lane >> 4, l15 = lane & 15;
    const int wm = wave >> 1, wn = wave & 1;

    const int lin = blockIdx.x + 16 * blockIdx.y;   // 0..511
    const int xcd = lin & 7, jj = lin >> 3;         // jj in 0..63
    const int gx = xcd & 1, gy = xcd >> 1;          // 2 x 4 chunk grid
    const int bx = gx * 8 + (jj >> 3);              // 8 bx-panels per XCD
    const int by = gy * 8 + (jj & 7);               // 8 by-panels per XCD
    const int K = 1024;

    const int srow = lane >> 3;
    const int sp   = lane & 7;
    const int scl  = sp ^ srow;
    const int sw   = l15 & 7;

    f32x4 acc[4][2];
#pragma unroll
    for (int i = 0; i < 4; ++i)
#pragma unroll
        for (int j = 0; j < 2; ++j) acc[i][j] = (f32x4)(0.0f);

    for (int KT = 0; KT < 8; ++KT) {
        __syncthreads();
#pragma unroll
        for (int t2 = 0; t2 < 2; ++t2) {
            int kt = KT * 2 + t2;
#pragma unroll
            for (int j = 0; j < 4; ++j) {
                int r0 = wave * 32 + j * 8;
                async16(A + (size_t)(by * 128 + r0 + srow) * K + kt * 64 + scl * 8,
                        &As[t2 * 8192 + r0 * 64]);
            }
#pragma unroll
            for (int j = 0; j < 2; ++j) {
                int r0 = wave * 16 + j * 8;
                async16(B + (size_t)(bx * 64 + r0 + srow) * K + kt * 64 + scl * 8,
                        &Bs[t2 * 4096 + r0 * 64]);
            }
        }
        __syncthreads();

#pragma unroll
        for (int t2 = 0; t2 < 2; ++t2) {
            const unsigned short* AsJ = &As[t2 * 8192];
            const unsigned short* BsJ = &Bs[t2 * 4096];
#pragma unroll
            for (int kh = 0; kh < 2; ++kh) {
                f16x8 af[4], bfr[2];
#pragma unroll
                for (int mi = 0; mi < 4; ++mi)
                    af[mi] = __builtin_bit_cast(f16x8,
                        *(const ushort8*)&AsJ[(wm * 64 + mi * 16 + l15) * 64 + ((kh * 4 + quad) ^ sw) * 8]);
#pragma unroll
                for (int ni = 0; ni < 2; ++ni)
                    bfr[ni] = __builtin_bit_cast(f16x8,
                        *(const ushort8*)&BsJ[(wn * 32 + ni * 16 + l15) * 64 + ((kh * 4 + quad) ^ sw) * 8]);
#pragma unroll
                for (int mi = 0; mi < 4; ++mi)
#pragma unroll
                    for (int ni = 0; ni < 2; ++ni)
                        acc[mi][ni] = __builtin_amdgcn_mfma_f32_16x16x32_f16(af[mi], bfr[ni], acc[mi][ni], 0, 0, 0);
            }
        }
    }

#pragma unroll
    for (int ni = 0; ni < 2; ++ni) {
        int n = bx * 64 + wn * 32 + ni * 16 + l15;
        float bias = bo[n];
#pragma unroll
        for (int mi = 0; mi < 4; ++mi) {
#pragma unroll
            for (int r = 0; r < 4; ++r) {
                int m = by * 128 + wm * 64 + mi * 16 + quad * 4 + r;
                Cout[(size_t)m * 1024 + n] = acc[mi][ni][r] + bias;
            }
        }
    }
}

// ---------------- flash attention: r17 + MFMA l-sum (r20) ----------------
// r13 structure + XCD remap + setprio + f16 ctx. r20: the l row-sum moves from the
// VALU (32 adds/tile + epilogue shfl_xor) to the MFMA pipe via the ones-row trick:
// lones[s] = mfma(ones8, p8, lones[s]) computes sum_k p[k][qcol] for every q-column
// (k-reduction inside the MFMA across lanes), so each lane directly holds the
// full-k l for its q-row (l15) — no cross-lane reduce needed. VALU was the hottest
// pipe (45%); MFMA at 27% has headroom. l is summed from the same f16 p that PV
// consumes (self-consistent normalization).
__global__ __launch_bounds__(256) void attn(const unsigned short* __restrict__ qkv,
                                            const _Float16* __restrict__ vtg,
                                            _Float16* __restrict__ ctx)
{
    __shared__ __align__(16) unsigned short Ks[4 * 64 * 64];
    __shared__ __align__(16) _Float16 Vt[4 * 64 * 64];

    const int tid  = threadIdx.x;
    const int lane = tid & 63, wave = tid >> 6;
    const int quad = lane >> 4, l15 = lane & 15;

    const int lin = blockIdx.x + 16 * blockIdx.y;   // 0..511
    const int xcd = lin & 7, jj = lin >> 3;         // jj in 0..63
    const int bh = xcd * 4 + (jj >> 4);             // 4 heads per XCD
    const int b = bh >> 4, h = bh & 15;
    const int q0 = (jj & 15) * 128;

    const int srow = lane >> 3;
    const int sp   = lane & 7;
    const int scl  = sp ^ srow;
    const int sw   = l15 & 7;

    bf16x8 qf[2][2];
#pragma unroll
    for (int s = 0; s < 2; ++s) {
        int qrow = b * 2048 + q0 + wave * 32 + s * 16 + l15;
#pragma unroll
        for (int kh = 0; kh < 2; ++kh)
            qf[s][kh] = __builtin_bit_cast(bf16x8,
                *(const ushort8*)(qkv + (size_t)qrow * 2048 + h * 64 + kh * 32 + quad * 8));
    }

    f32x4 ot[2][4];
#pragma unroll
    for (int s = 0; s < 2; ++s)
#pragma unroll
        for (int ht = 0; ht < 4; ++ht) ot[s][ht] = (f32x4)(0.0f);
    f32x4 lones[2] = {(f32x4)(0.0f), (f32x4)(0.0f)};
    const f16x8 ones8 = {(_Float16)1.0f, (_Float16)1.0f, (_Float16)1.0f, (_Float16)1.0f,
                         (_Float16)1.0f, (_Float16)1.0f, (_Float16)1.0f, (_Float16)1.0f};

    for (int KT = 0; KT < 8; ++KT) {
        __syncthreads();
#pragma unroll
        for (int j = 0; j < 4; ++j) {
            int kt = KT * 4 + j;
#pragma unroll
            for (int i = 0; i < 2; ++i) {
                int row = i * 32 + wave * 8 + srow;
                async16(qkv + (size_t)(b * 2048 + kt * 64 + row) * 2048 + 1024 + h * 64 + scl * 8,
                        &Ks[j * 4096 + (i * 32 + wave * 8) * 64]);
                async16(vtg + (size_t)(bh * 64 + row) * 2048 + kt * 64 + sp * 8,
                        (unsigned short*)&Vt[j * 4096 + (i * 32 + wave * 8) * 64]);
            }
        }
        __syncthreads();

        __builtin_amdgcn_s_setprio(1);
#pragma unroll
        for (int j = 0; j < 4; ++j) {
            const unsigned short* KsJ = &Ks[j * 4096];
            const _Float16*       VtJ = &Vt[j * 4096];

            f16x4 pv[2][4];
#pragma unroll
            for (int mt = 0; mt < 4; ++mt) {
                const unsigned short* kb = &KsJ[(mt * 16 + l15) * 64];
                bf16x8 k0 = __builtin_bit_cast(bf16x8, *(const ushort8*)(kb + (quad ^ sw) * 8));
                bf16x8 k1 = __builtin_bit_cast(bf16x8, *(const ushort8*)(kb + ((quad ^ sw) ^ 4) * 8));
#pragma unroll
                for (int s = 0; s < 2; ++s) {
                    f32x4 s4 = (f32x4)(0.0f);
                    s4 = __builtin_amdgcn_mfma_f32_16x16x32_bf16(k0, qf[s][0], s4, 0, 0, 0);
                    s4 = __builtin_amdgcn_mfma_f32_16x16x32_bf16(k1, qf[s][1], s4, 0, 0, 0);
                    float p0 = __builtin_amdgcn_exp2f(s4[0]);
                    float p1 = __builtin_amdgcn_exp2f(s4[1]);
                    float p2 = __builtin_amdgcn_exp2f(s4[2]);
                    float p3 = __builtin_amdgcn_exp2f(s4[3]);
                    fp16v2 lo = __builtin_amdgcn_cvt_pkrtz(p0, p1);
                    fp16v2 hi = __builtin_amdgcn_cvt_pkrtz(p2, p3);
                    f16x2 lo2 = __builtin_bit_cast(f16x2, lo);
                    f16x2 hi2 = __builtin_bit_cast(f16x2, hi);
                    pv[s][mt] = __builtin_shufflevector(lo2, hi2, 0, 1, 2, 3);
                }
            }

#pragma unroll
            for (int g = 0; g < 2; ++g) {
#pragma unroll
                for (int s = 0; s < 2; ++s) {
                    f16x8 p8 = __builtin_shufflevector(pv[s][2 * g], pv[s][2 * g + 1],
                                                       0, 1, 2, 3, 4, 5, 6, 7);
                    lones[s] = __builtin_amdgcn_mfma_f32_16x16x32_f16(ones8, p8, lones[s], 0, 0, 0);
#pragma unroll
                    for (int ht = 0; ht < 4; ++ht) {
                        const _Float16* vb = &VtJ[(ht * 16 + l15) * 64];
                        f16x8 v8 = *(const f16x8*)(vb + (((g * 4 + quad) ^ sw)) * 8);
                        ot[s][ht] = __builtin_amdgcn_mfma_f32_16x16x32_f16(v8, p8, ot[s][ht], 0, 0, 0);
                    }
                }
            }
        }
        __builtin_amdgcn_s_setprio(0);
    }

#pragma unroll
    for (int s = 0; s < 2; ++s) {
        float inv = 1.0f / lones[s][0];   // every lane holds full-k l for q-row l15
        int qrow = b * 2048 + q0 + wave * 32 + s * 16 + l15;
#pragma unroll
        for (int ht = 0; ht < 4; ++ht) {
            f16x4 o4;
#pragma unroll
            for (int r = 0; r < 4; ++r) o4[r] = (_Float16)(ot[s][ht][r] * inv);
            *(f16x4*)(ctx + (size_t)qrow * 1024 + h * 64 + ht * 16 + quad * 4) = o4;
        }
    }
}

extern "C" void kernel_launch(void* const* d_in, const int* in_sizes, int n_in,
                              void* d_out, int out_size, void* d_ws, size_t ws_size,
                              hipStream_t stream) {
    const float* query = (const float*)d_in[0];
    const float* Wq = (const float*)d_in[1];
    const float* bq = (const float*)d_in[2];
    const float* Wk = (const float*)d_in[3];
    const float* bk = (const float*)d_in[4];
    const float* Wv = (const float*)d_in[5];
    const float* bv = (const float*)d_in[6];
    const float* Wo = (const float*)d_in[7];
    const float* bo = (const float*)d_in[8];

    char* ws = (char*)d_ws;
    unsigned short* q_bf  = (unsigned short*)(ws);                 // 8 MB (dead after qkv_gemm)
    _Float16*       ctx   = (_Float16*)(ws);                       // aliases q_bf (attn writes after q_bf dead)
    unsigned short* wqkv  = (unsigned short*)(ws + 8388608);       // 6 MB
    unsigned short* wo_f  = (unsigned short*)(ws + 14680064);      // 2 MB (f16)
    unsigned short* qkv   = (unsigned short*)(ws + 16777216);      // [4096][2048] bf16 = 16 MB (Q,K only)
    _Float16*       vtg   = (_Float16*)(ws + 33554432);            // [32][64][2048] f16 = 8 MB

    const float SCALE = 0.125f * 1.4426950408889634f;   // (1/sqrt(hd)) * log2(e), folded into K

    cvt_all<<<8192, 256, 0, stream>>>(query, Wq, Wk, Wv, Wo, q_bf, wqkv, wo_f, SCALE);
    qkv_gemm<<<dim3(24, 32), 256, 0, stream>>>(q_bf, wqkv, qkv, vtg, bq, bk, bv, SCALE);
    attn<<<dim3(16, 32), 256, 0, stream>>>(qkv, vtg, ctx);
    out_gemm<<<dim3(16, 32), 256, 0, stream>>>(ctx, wo_f, (float*)d_out, bo);
}